// Round 12
// baseline (9470.327 us; speedup 1.0000x reference)
//
#include <hip/hip_runtime.h>

typedef unsigned short u16;
typedef unsigned int u32;

#define NT 1024
#define Bv 32
#define Tv 256
#define Wv 128
#define Rv 4
#define Nv 128
#define DELTAv 1e-6f

__device__ __forceinline__ float bf2f(u16 u){
  union { u32 i; float f; } c; c.i = ((u32)u) << 16; return c.f;
}
__device__ __forceinline__ u16 f2bf(float f){
  union { float f; u32 u; } c; c.f = f;
  u32 u = c.u;
  return (u16)((u + 0x7fffu + ((u >> 16) & 1u)) >> 16);
}
__device__ __forceinline__ void unp(u32 v, float& a, float& b){
  union { u32 i; float f; } c0, c1;
  c0.i = v << 16; c1.i = v & 0xffff0000u;
  a = c0.f; b = c1.f;
}
__device__ __forceinline__ float sigm(float x){ return 1.0f / (1.0f + __expf(-x)); }
__device__ __forceinline__ float softplusf(float x){ return fmaxf(x, 0.f) + log1pf(__expf(-fabsf(x))); }
__device__ __forceinline__ float wredsum(float v){
  #pragma unroll
  for (int o = 32; o > 0; o >>= 1) v += __shfl_down(v, o, 64);
  return v;
}
__device__ __forceinline__ float wredmax(float v){
  #pragma unroll
  for (int o = 32; o > 0; o >>= 1) v = fmaxf(v, __shfl_down(v, o, 64));
  return v;
}
__device__ __forceinline__ float ldval(const void* p, int idx, int dt32){
  return dt32 ? ((const float*)p)[idx] : bf2f(((const u16*)p)[idx]);
}
// wave-broadcast from per-lane register file (lane index literal via unroll)
__device__ __forceinline__ float rl(float v, int l){
  union { int i; float f; } c;
  c.i = __builtin_amdgcn_readlane(__float_as_int(v), l);
  return c.f;
}

// single-output 8-deep prefetch GEMV partial (bf16-pair weights)
template<int ITERS, int STRIDE>
__device__ __forceinline__ float gemv_bf(const u32* __restrict__ wp, const float* __restrict__ xp){
  float a0 = 0.f, a1 = 0.f;
  u32 wb[8];
  #pragma unroll
  for (int i = 0; i < 8; i++) wb[i] = wp[i * STRIDE];
  #pragma unroll 1
  for (int c = 0; c < ITERS - 8; c += 8){
    u32 wn[8];
    #pragma unroll
    for (int i = 0; i < 8; i++) wn[i] = wp[(c + 8 + i) * STRIDE];
    #pragma unroll
    for (int i = 0; i < 8; i++){
      float w0, w1; unp(wb[i], w0, w1);
      float2 x2 = *(const float2*)(xp + 2 * (c + i));
      a0 = fmaf(x2.x, w0, a0); a1 = fmaf(x2.y, w1, a1);
      wb[i] = wn[i];
    }
  }
  #pragma unroll
  for (int i = 0; i < 8; i++){
    float w0, w1; unp(wb[i], w0, w1);
    float2 x2 = *(const float2*)(xp + 2 * (ITERS - 8 + i));
    a0 = fmaf(x2.x, w0, a0); a1 = fmaf(x2.y, w1, a1);
  }
  return a0 + a1;
}

// dual-output GEMV partial: two weight streams share one x-read
template<int ITERS, int STRIDE>
__device__ __forceinline__ void gemv2_bf(const u32* __restrict__ wp0, const u32* __restrict__ wp1,
                                         const float* __restrict__ xp, float& r0, float& r1){
  float a0 = 0.f, a1 = 0.f, b0 = 0.f, b1 = 0.f;
  u32 wa[4], wb[4];
  #pragma unroll
  for (int i = 0; i < 4; i++){ wa[i] = wp0[i * STRIDE]; wb[i] = wp1[i * STRIDE]; }
  #pragma unroll 1
  for (int c = 0; c < ITERS - 4; c += 4){
    u32 na[4], nb[4];
    #pragma unroll
    for (int i = 0; i < 4; i++){ na[i] = wp0[(c + 4 + i) * STRIDE]; nb[i] = wp1[(c + 4 + i) * STRIDE]; }
    #pragma unroll
    for (int i = 0; i < 4; i++){
      float2 x2 = *(const float2*)(xp + 2 * (c + i));
      float w0, w1;
      unp(wa[i], w0, w1);
      a0 = fmaf(x2.x, w0, a0); a1 = fmaf(x2.y, w1, a1);
      unp(wb[i], w0, w1);
      b0 = fmaf(x2.x, w0, b0); b1 = fmaf(x2.y, w1, b1);
      wa[i] = na[i]; wb[i] = nb[i];
    }
  }
  #pragma unroll
  for (int i = 0; i < 4; i++){
    float2 x2 = *(const float2*)(xp + 2 * (ITERS - 4 + i));
    float w0, w1;
    unp(wa[i], w0, w1);
    a0 = fmaf(x2.x, w0, a0); a1 = fmaf(x2.y, w1, a1);
    unp(wb[i], w0, w1);
    b0 = fmaf(x2.x, w0, b0); b1 = fmaf(x2.y, w1, b1);
  }
  r0 = a0 + a1; r1 = b0 + b1;
}

// ---- dtype detect (flag=1 -> fp32 tensors, 0 -> bf16) ----
__global__ void detect_dtype(const u16* __restrict__ buf, int* __restrict__ flag){
  int lane = threadIdx.x;
  float crazy = 0.f;
  for (int i = 0; i < 4; i++){
    u16 v = buf[lane * 4 + i];
    int e = (v >> 7) & 0xFF;
    if (e != 0 && (e < 117 || e > 137)) crazy += 1.f;
  }
  crazy = wredsum(crazy);
  if (lane == 0) flag[0] = (crazy >= 32.f) ? 1 : 0;
}

__device__ __forceinline__ u16 rdbf(const void* s, size_t idx, int f32){
  return f32 ? f2bf(((const float*)s)[idx]) : ((const u16*)s)[idx];
}

__global__ void pack_w(const void* __restrict__ src, u32* __restrict__ dst,
                       int Js, int Jd, int K, const int* __restrict__ flag){
  int j = blockIdx.x * 256 + threadIdx.x;
  int k2 = blockIdx.y;
  if (j >= Jd) return;
  u16 lo = 0, hi = 0;
  if (j < Js){
    lo = rdbf(src, (size_t)j * K + 2 * k2, flag[0]);
    hi = rdbf(src, (size_t)j * K + 2 * k2 + 1, flag[0]);
  }
  dst[(size_t)k2 * Jd + j] = (u32)lo | ((u32)hi << 16);
}

__device__ __forceinline__ int permctl(int c){
  if (c < 128) return 5 * c;
  int q = c - 128; return 5 * (q & 127) + 1 + (q >> 7);
}
__device__ __forceinline__ int permout(int c){
  if (c < 128) return c;
  int q = c - 128; return 128 + 4 * (q & 127) + (q >> 7);
}

__global__ void pack_ctl(const void* __restrict__ src, u32* __restrict__ dst,
                         const int* __restrict__ flag){
  int j = blockIdx.x * 256 + threadIdx.x;
  int k2 = blockIdx.y;
  if (j >= 512) return;
  u16 lo = rdbf(src, (size_t)j * 640 + permctl(2 * k2), flag[0]);
  u16 hi = rdbf(src, (size_t)j * 640 + permctl(2 * k2 + 1), flag[0]);
  dst[(size_t)k2 * 512 + j] = (u32)lo | ((u32)hi << 16);
}

__global__ void pack_out(const void* __restrict__ src, u32* __restrict__ dst,
                         const int* __restrict__ flag){
  int j = threadIdx.x;
  int k2 = blockIdx.y;
  if (j >= 128) return;
  u16 lo = rdbf(src, (size_t)j * 640 + permout(2 * k2), flag[0]);
  u16 hi = rdbf(src, (size_t)j * 640 + permout(2 * k2 + 1), flag[0]);
  dst[(size_t)k2 * 128 + j] = (u32)lo | ((u32)hi << 16);
}

__global__ void fill_half(u16* __restrict__ p, int n){
  int i = blockIdx.x * 256 + threadIdx.x;
  if (i < n) p[i] = 0x3F00;
}

__global__ __launch_bounds__(NT) void dnc_main(
    const void* __restrict__ input,
    const void* __restrict__ enc_bih_g, const void* __restrict__ enc_bhh_g,
    const void* __restrict__ ctl_bih_g, const void* __restrict__ ctl_bhh_g,
    const void* __restrict__ iface_b_g, const void* __restrict__ out_b_g,
    const u32* __restrict__ encPW, const u32* __restrict__ ctlPW,
    const u32* __restrict__ ifPW, const u32* __restrict__ outPW,
    void* __restrict__ outp, const int* __restrict__ dtflag)
{
  const int bid = blockIdx.x;   // owner batch
  const int tid = threadIdx.x;
  const int lane = tid & 63;
  const int wid = tid >> 6;
  const int dt32 = dtflag[0];

  __shared__ __align__(16) float memS[Nv * 129];
  __shared__ __align__(16) float linkS[Nv * 129];
  __shared__ __align__(16) float pp[NT];
  __shared__ __align__(16) float ppE[NT];   // [0..256): out rv-part; [512..1024): out h-part
  __shared__ __align__(16) float xhC[768];  // [hE(128); rv r-major(512); hC(128)]
  __shared__ __align__(16) float xin2[2][128];
  __shared__ __align__(16) float rkeyS[512], rwS[512], rcS[512];
  __shared__ __align__(16) float wkeyS[128], eraseS[128], wvecS[128];
  __shared__ __align__(16) float wwS[128], usageS[128], precS[128];
  __shared__ __align__(16) float uS[128], sortedU[128], scanA[128], alS[128], sqS[128];
  __shared__ __align__(16) float encBias[512], ctlBias[512];
  __shared__ __align__(16) float outBias[128];
  __shared__ float rstrS[4], fgS[4], rmRaw[12], rmS[12], scal[16];

  float cE = 0.f;   // enc cell: tids 896-1023
  float cC = 0.f;   // ctl cell: tids 0-127

  // inline xi scatter with activations (c in [0,919))
  auto scatter_xi = [&](int c, float v){
    if (c < 512) rkeyS[c] = tanhf(v);
    else if (c < 516) rstrS[c - 512] = softplusf(v);
    else if (c < 644) wkeyS[c - 516] = tanhf(v);
    else if (c == 644) scal[0] = softplusf(v);
    else if (c < 773) eraseS[c - 645] = sigm(v);
    else if (c < 901) wvecS[c - 773] = tanhf(v);
    else if (c < 905) fgS[c - 901] = sigm(v);
    else if (c == 905) scal[1] = sigm(v);
    else if (c == 906) scal[2] = sigm(v);
    else rmRaw[c - 907] = v;
  };

  // ---- init ----
  if (tid < 512){
    encBias[tid] = ldval(enc_bih_g, tid, dt32) + ldval(enc_bhh_g, tid, dt32);
    ctlBias[tid] = ldval(ctl_bih_g, tid, dt32) + ldval(ctl_bhh_g, tid, dt32);
    rwS[tid] = 0.f;
  }
  if (tid < 768) xhC[tid] = 0.f;
  if (tid < 128){
    outBias[tid] = ldval(out_b_g, tid, dt32);
    wwS[tid] = 0.f; usageS[tid] = 0.f; precS[tid] = 0.f;
  }
  for (int i = tid; i < Nv * 129; i += NT){ memS[i] = 0.f; linkS[i] = 0.f; }
  if (tid < 64){   // x(0) -> xin2[0]
    int idx = (bid * Tv + 0) * Wv + 2 * tid;
    xin2[0][2 * tid] = ldval(input, idx, dt32);
    xin2[0][2 * tid + 1] = ldval(input, idx + 1, dt32);
  } else if (tid >= 64 && tid < 128){   // x(1) -> xin2[1]
    int w2 = (tid - 64) * 2;
    int idx = (bid * Tv + 1) * Wv + w2;
    xin2[1][w2] = ldval(input, idx, dt32);
    xin2[1][w2 + 1] = ldval(input, idx + 1, dt32);
  }
  __syncthreads();

  // ---- preamble: encoder step 0 (Wih*x(0); Whh*0) ----
  if (tid >= 512 && tid < 768){
    int o = tid - 512;
    float r0, r1;
    gemv2_bf<64, 512>(encPW + o, encPW + o + 256, xin2[0], r0, r1);
    rcS[o] = r0; rcS[o + 256] = r1;
  }
  __syncthreads();
  if (tid >= 896){
    int w = tid - 896;
    float g0 = rcS[w] + encBias[w];
    float g1 = rcS[128 + w] + encBias[128 + w];
    float g2 = rcS[256 + w] + encBias[256 + w];
    float g3 = rcS[384 + w] + encBias[384 + w];
    float cn = sigm(g1) * cE + sigm(g0) * tanhf(g2);
    cE = cn;
    xhC[w] = sigm(g3) * tanhf(cn);   // hE(0)
  }
  __syncthreads();

  // =========================== main loop (9 barriers/step) ===========================
  for (int t = 0; t < Tv; ++t){
    // Ph1: ctl GEMV (w0-7) || enc Wih*x(t+1) (w8-11) || out-rv GEMV for t-1 (w12-15)
    if (tid < 512){
      int s = tid >> 8, o = tid & 255;
      float r0, r1;
      gemv2_bf<192, 512>(ctlPW + (s * 192) * 512 + o, ctlPW + (s * 192) * 512 + o + 256,
                         xhC + s * 384, r0, r1);
      pp[s * 512 + o] = r0;
      pp[s * 512 + o + 256] = r1;
    } else if (tid < 768){
      int o = tid - 512;
      float r0, r1;
      gemv2_bf<64, 512>(encPW + o, encPW + o + 256, xin2[(t + 1) & 1], r0, r1);
      rcS[o] = r0; rcS[o + 256] = r1;
    } else {
      int q = tid - 768;   // 256 threads
      int s = q >> 7, j = q & 127;
      ppE[q] = gemv_bf<128, 128>(outPW + (64 + s * 128) * 128 + j, xhC + 128 + 256 * s);
    }
    __syncthreads();

    // Ph2: ctl pointwise (0-127) || out(t-1) store (128-255) || enc Whh+combine (512-767) || stage x(t+2) (768-831)
    if (tid < 128){
      float g0 = pp[tid] + pp[512 + tid] + ctlBias[tid];
      float g1 = pp[128 + tid] + pp[640 + tid] + ctlBias[128 + tid];
      float g2 = pp[256 + tid] + pp[768 + tid] + ctlBias[256 + tid];
      float g3 = pp[384 + tid] + pp[896 + tid] + ctlBias[384 + tid];
      float cn = sigm(g1) * cC + sigm(g0) * tanhf(g2);
      cC = cn;
      xhC[640 + tid] = sigm(g3) * tanhf(cn);   // hC(t)
    } else if (tid < 256){
      if (t > 0){
        int w = tid - 128;
        float o = outBias[w] + ppE[w] + ppE[128 + w]
                + ppE[512 + w] + ppE[640 + w] + ppE[768 + w] + ppE[896 + w];
        size_t oi = ((size_t)bid * Tv + (t - 1)) * Wv + w;
        if (dt32) ((float*)outp)[oi] = o;
        else ((u16*)outp)[oi] = f2bf(o);
      }
    } else if (tid >= 512 && tid < 768){
      int o = tid - 512;
      float r0, r1;
      gemv2_bf<64, 512>(encPW + 64 * 512 + o, encPW + 64 * 512 + o + 256, xhC, r0, r1);
      rcS[o] = rcS[o] + r0;
      rcS[o + 256] = rcS[o + 256] + r1;
    } else if (tid >= 768 && tid < 832){
      int w2 = (tid - 768) * 2;
      int col = (t + 2 < Tv) ? t + 2 : Tv - 1;
      int idx = (bid * Tv + col) * Wv + w2;
      xin2[t & 1][w2] = ldval(input, idx, dt32);
      xin2[t & 1][w2 + 1] = ldval(input, idx + 1, dt32);
    }
    __syncthreads();

    // Ph3: iface GEMV + INLINE activation/scatter (0-463) || enc pointwise -> hE(t+1) (896-1023)
    if (tid < 464){
      float r0, r1;
      gemv2_bf<64, 928>(ifPW + tid, ifPW + tid + 464, xhC + 640, r0, r1);
      scatter_xi(tid, r0 + ldval(iface_b_g, tid, dt32));
      int c1 = tid + 464;
      if (c1 < 919) scatter_xi(c1, r1 + ldval(iface_b_g, c1, dt32));
    } else if (tid >= 896){
      int w = tid - 896;
      float g0 = rcS[w] + encBias[w];
      float g1 = rcS[128 + w] + encBias[128 + w];
      float g2 = rcS[256 + w] + encBias[256 + w];
      float g3 = rcS[384 + w] + encBias[384 + w];
      float cn = sigm(g1) * cE + sigm(g0) * tanhf(g2);
      cE = cn;
      xhC[w] = sigm(g3) * tanhf(cn);   // hE(t+1)
    }
    __syncthreads();

    // Ph4 (mega): wc-dot partials (0-255) | rkey norms (256-511) | wkey norm (512-575)
    //  | old-mem sq partials (576-831) | usage+uS+rank+scan+alloc (wave 13) | rm softmax (896-899)
    if (tid < 256){
      int n = tid & 127, hf = tid >> 7;
      float wk = wkeyS[hf * 64 + lane];
      const float* mrow = memS + n * 129 + hf * 64;
      float dt = 0.f;
      #pragma unroll 64
      for (int jj = 0; jj < 64; jj++) dt = fmaf(rl(wk, jj), mrow[jj], dt);
      pp[tid] = dt;
    } else if (tid < 512){
      int r = wid - 4;
      float a = rkeyS[r * 128 + lane], b = rkeyS[r * 128 + 64 + lane];
      float s = wredsum(a * a + b * b);
      if (lane == 0) scal[4 + r] = 1.f / (sqrtf(s) + DELTAv);
    } else if (tid < 576){
      float a = wkeyS[lane], b = wkeyS[64 + lane];
      float s = wredsum(a * a + b * b);
      if (lane == 0) scal[8] = 1.f / (sqrtf(s) + DELTAv);
    } else if (tid < 832){
      int q = tid - 576;
      int n = q & 127, hf = q >> 7;
      const float* mrow = memS + n * 129 + hf * 64;
      float sq = 0.f;
      #pragma unroll 64
      for (int jj = 0; jj < 64; jj++){ float m = mrow[jj]; sq = fmaf(m, m, sq); }
      pp[512 + q] = sq;
    } else if (tid < 896){
      // wave 13: usage + uS, then rank + scan + alloc (same-wave LDS ordering)
      int l = lane;
      float us0 = usageS[l], us1 = usageS[64 + l];
      us0 = us0 + (1.f - us0) * wwS[l];
      us1 = us1 + (1.f - us1) * wwS[64 + l];
      float ret0 = (1.f - fgS[0] * rwS[l]) * (1.f - fgS[1] * rwS[128 + l]) *
                   (1.f - fgS[2] * rwS[256 + l]) * (1.f - fgS[3] * rwS[384 + l]);
      float ret1 = (1.f - fgS[0] * rwS[64 + l]) * (1.f - fgS[1] * rwS[192 + l]) *
                   (1.f - fgS[2] * rwS[320 + l]) * (1.f - fgS[3] * rwS[448 + l]);
      us0 *= ret0; us1 *= ret1;
      usageS[l] = us0; usageS[64 + l] = us1;
      float u0 = DELTAv + (1.f - DELTAv) * us0;
      float u1 = DELTAv + (1.f - DELTAv) * us1;
      uS[l] = u0; uS[64 + l] = u1;
      int r0 = 0, r1 = 0;
      for (int m = 0; m < 128; m++){
        float um = uS[m];
        r0 += (um < u0) || (um == u0 && m < l);
        r1 += (um < u1) || (um == u1 && m < 64 + l);
      }
      sortedU[r0] = u0; sortedU[r1] = u1;
      float a = sortedU[2 * l], bq = sortedU[2 * l + 1];
      float p = a * bq;
      float incl = p;
      #pragma unroll
      for (int o = 1; o < 64; o <<= 1){
        float tv = __shfl_up(incl, o, 64);
        if (l >= o) incl *= tv;
      }
      float exh = __shfl_up(incl, 1, 64);
      if (l == 0) exh = 1.f;
      scanA[2 * l] = exh;
      scanA[2 * l + 1] = exh * a;
      float ex0 = scanA[r0], ex1 = scanA[r1];
      alS[l] = (1.f - u0) * ex0;
      alS[64 + l] = (1.f - u1) * ex1;
    } else if (tid < 900){
      int r = tid - 896;
      float m0 = rmRaw[3 * r], m1 = rmRaw[3 * r + 1], m2 = rmRaw[3 * r + 2];
      float mx = fmaxf(m0, fmaxf(m1, m2));
      float e0 = __expf(m0 - mx), e1 = __expf(m1 - mx), e2 = __expf(m2 - mx);
      float s = e0 + e1 + e2;
      rmS[3 * r] = e0 / s; rmS[3 * r + 1] = e1 / s; rmS[3 * r + 2] = e2 / s;
    }
    __syncthreads();

    // Ph5: single wave — wc finalize + softmax + write weighting + sum
    if (wid == 0){
      float d0 = pp[lane] + pp[128 + lane];
      float d1 = pp[64 + lane] + pp[192 + lane];
      float q0 = pp[512 + lane] + pp[640 + lane];
      float q1 = pp[576 + lane] + pp[704 + lane];
      float kfac = scal[8] * scal[0];   // invKw * write_str
      float a  = d0 / (sqrtf(q0) + DELTAv) * kfac;
      float bq = d1 / (sqrtf(q1) + DELTAv) * kfac;
      float mx = wredmax(fmaxf(a, bq)); mx = __shfl(mx, 0, 64);
      float ea = __expf(a - mx), eb = __expf(bq - mx);
      float s = wredsum(ea + eb); s = __shfl(s, 0, 64);
      float wc0 = ea / s, wc1 = eb / s;
      float w0v = scal[2] * (scal[1] * alS[lane] + (1.f - scal[1]) * wc0);
      float w1v = scal[2] * (scal[1] * alS[64 + lane] + (1.f - scal[1]) * wc1);
      wwS[lane] = w0v; wwS[64 + lane] = w1v;
      float s2 = wredsum(w0v + w1v);
      if (lane == 0) scal[3] = s2;
    }
    __syncthreads();

    // Ph6: mem erase/write + link update (16 waves)
    #pragma unroll
    for (int it = 0; it < 16; it++){
      int e = it * NT + tid;
      int n = e >> 7, w = e & 127;
      float wwn = wwS[n];
      float m = memS[n * 129 + w];
      memS[n * 129 + w] = m * (1.f - wwn * eraseS[w]) + wwn * wvecS[w];
      float l = linkS[n * 129 + w];
      linkS[n * 129 + w] = (n == w) ? 0.f
        : ((1.f - wwn - wwS[w]) * l + wwn * precS[w]);
    }
    __syncthreads();

    // Ph7: fw+bw 1 head/thread (0-511) || rc 1 head/thread + sq (512-1023)
    if (tid < 512){
      int r = wid >> 1, i = tid & 127;
      float rw0 = rwS[r * 128 + lane], rw1 = rwS[r * 128 + 64 + lane];
      float f = 0.f, b = 0.f;
      #pragma unroll 128
      for (int j = 0; j < 128; j++){
        float lr = linkS[i * 129 + j];
        float lc = linkS[j * 129 + i];
        float w = rl((j < 64) ? rw0 : rw1, j & 63);
        f = fmaf(w, lr, f); b = fmaf(w, lc, b);
      }
      pp[r * 128 + i] = f;
      pp[512 + r * 128 + i] = b;
    } else {
      int q = tid - 512;
      int r = q >> 7, n = q & 127;
      float k0 = rkeyS[r * 128 + lane], k1 = rkeyS[r * 128 + 64 + lane];
      float sq = 0.f, d = 0.f;
      #pragma unroll 128
      for (int j = 0; j < 128; j++){
        float m = memS[n * 129 + j];
        if (r == 0) sq = fmaf(m, m, sq);
        d = fmaf(rl((j < 64) ? k0 : k1, j & 63), m, d);
      }
      rcS[r * 128 + n] = d;
      if (r == 0) sqS[n] = sq;
    }
    __syncthreads();

    // Ph8: scaled rc softmax + new rw (w0-3) || prec (256-383) || out-h GEMV (512-1023)
    if (wid < 4){
      int r = wid;
      float fac = scal[4 + r] * rstrS[r];
      float im0 = 1.f / (sqrtf(sqS[lane]) + DELTAv);
      float im1 = 1.f / (sqrtf(sqS[64 + lane]) + DELTAv);
      float a  = rcS[r * 128 + lane] * im0 * fac;
      float bq = rcS[r * 128 + 64 + lane] * im1 * fac;
      float mx = wredmax(fmaxf(a, bq)); mx = __shfl(mx, 0, 64);
      float ea = __expf(a - mx), eb = __expf(bq - mx);
      float s = wredsum(ea + eb); s = __shfl(s, 0, 64);
      float pa = ea / s, pb = eb / s;
      int o0 = r * 128 + lane, o1 = o0 + 64;
      rwS[o0] = rmS[3 * r] * pp[512 + o0] + rmS[3 * r + 1] * pp[o0] + rmS[3 * r + 2] * pa;
      rwS[o1] = rmS[3 * r] * pp[512 + o1] + rmS[3 * r + 1] * pp[o1] + rmS[3 * r + 2] * pb;
    } else if (tid >= 256 && tid < 384){
      int n = tid - 256;
      precS[n] = (1.f - scal[3]) * precS[n] + wwS[n];
    } else if (tid >= 512){
      int s = (tid - 512) >> 7, j = tid & 127;
      ppE[tid] = gemv_bf<16, 128>(outPW + (s * 16) * 128 + j, xhC + 640 + 32 * s);
    }
    __syncthreads();

    // Ph9: rv full-K readlane (w0-7) -> xhC rv slots
    if (tid < 512){
      int r = tid >> 7, w = tid & 127;
      float rw0 = rwS[r * 128 + lane], rw1 = rwS[r * 128 + 64 + lane];
      float acc = 0.f;
      #pragma unroll 128
      for (int n = 0; n < 128; n++)
        acc = fmaf(rl((n < 64) ? rw0 : rw1, n & 63), memS[n * 129 + w], acc);
      xhC[128 + tid] = acc;
    }
    __syncthreads();
  }

  // epilogue: out-rv for t = Tv-1, then final store
  if (tid < 256){
    int s = tid >> 7, j = tid & 127;
    ppE[tid] = gemv_bf<128, 128>(outPW + (64 + s * 128) * 128 + j, xhC + 128 + 256 * s);
  }
  __syncthreads();
  if (tid < 128){
    float o = outBias[tid] + ppE[tid] + ppE[128 + tid]
            + ppE[512 + tid] + ppE[640 + tid] + ppE[768 + tid] + ppE[896 + tid];
    size_t oi = ((size_t)bid * Tv + (Tv - 1)) * Wv + tid;
    if (dt32) ((float*)outp)[oi] = o;
    else ((u16*)outp)[oi] = f2bf(o);
  }
}

extern "C" void kernel_launch(void* const* d_in, const int* in_sizes, int n_in,
                              void* d_out, int out_size, void* d_ws, size_t ws_size,
                              hipStream_t stream) {
  (void)in_sizes; (void)n_in;
  const void* input   = d_in[0];
  const void* enc_Wih = d_in[2];
  const void* enc_Whh = d_in[3];
  const void* enc_bih = d_in[4];
  const void* enc_bhh = d_in[5];
  const void* ctl_Wih = d_in[6];
  const void* ctl_Whh = d_in[7];
  const void* ctl_bih = d_in[8];
  const void* ctl_bhh = d_in[9];
  const void* iface_W = d_in[10];
  const void* iface_b = d_in[11];
  const void* out_W   = d_in[12];
  const void* out_b   = d_in[13];

  char* ws = (char*)d_ws;
  size_t off = 0;
  int* dtflag = (int*)(ws + off); off += 256;
  u32* encPW = (u32*)(ws + off); off += (size_t)128 * 512 * 4;
  u32* ctlPW = (u32*)(ws + off); off += (size_t)384 * 512 * 4;
  u32* ifPW  = (u32*)(ws + off); off += (size_t)64 * 928 * 4;
  u32* outPW = (u32*)(ws + off); off += (size_t)320 * 128 * 4;
  const size_t need_bytes = off;   // ~1.45 MB (L2-resident)

  if (ws_size < need_bytes){
    fill_half<<<dim3((out_size + 255) / 256), dim3(256), 0, stream>>>((u16*)d_out, out_size);
    return;
  }

  detect_dtype<<<dim3(1), dim3(64), 0, stream>>>((const u16*)input, dtflag);

  pack_w<<<dim3(2, 64), 256, 0, stream>>>(enc_Wih, encPW, 512, 512, 128, dtflag);
  pack_w<<<dim3(2, 64), 256, 0, stream>>>(enc_Whh, encPW + 64 * 512, 512, 512, 128, dtflag);
  pack_ctl<<<dim3(2, 320), 256, 0, stream>>>(ctl_Wih, ctlPW, dtflag);
  pack_w<<<dim3(2, 64), 256, 0, stream>>>(ctl_Whh, ctlPW + 320 * 512, 512, 512, 128, dtflag);
  pack_w<<<dim3(4, 64), 256, 0, stream>>>(iface_W, ifPW, 919, 928, 128, dtflag);
  pack_out<<<dim3(1, 320), 128, 0, stream>>>(out_W, outPW, dtflag);

  dnc_main<<<dim3(Bv), dim3(NT), 0, stream>>>(
      input, enc_bih, enc_bhh, ctl_bih, ctl_bhh, iface_b, out_b,
      encPW, ctlPW, ifPW, outPW, d_out, dtflag);
}

// Round 13
// 8998.075 us; speedup vs baseline: 1.0525x; 1.0525x over previous
//
#include <hip/hip_runtime.h>

typedef unsigned short u16;
typedef unsigned int u32;

#define NT 1024
#define Bv 32
#define Tv 256
#define Wv 128
#define Rv 4
#define Nv 128
#define DELTAv 1e-6f

__device__ __forceinline__ float bf2f(u16 u){
  union { u32 i; float f; } c; c.i = ((u32)u) << 16; return c.f;
}
__device__ __forceinline__ u16 f2bf(float f){
  union { float f; u32 u; } c; c.f = f;
  u32 u = c.u;
  return (u16)((u + 0x7fffu + ((u >> 16) & 1u)) >> 16);
}
__device__ __forceinline__ void unp(u32 v, float& a, float& b){
  union { u32 i; float f; } c0, c1;
  c0.i = v << 16; c1.i = v & 0xffff0000u;
  a = c0.f; b = c1.f;
}
__device__ __forceinline__ float sigm(float x){ return 1.0f / (1.0f + __expf(-x)); }
__device__ __forceinline__ float softplusf(float x){ return fmaxf(x, 0.f) + log1pf(__expf(-fabsf(x))); }
__device__ __forceinline__ float wredsum(float v){
  #pragma unroll
  for (int o = 32; o > 0; o >>= 1) v += __shfl_down(v, o, 64);
  return v;
}
__device__ __forceinline__ float wredmax(float v){
  #pragma unroll
  for (int o = 32; o > 0; o >>= 1) v = fmaxf(v, __shfl_down(v, o, 64));
  return v;
}
__device__ __forceinline__ float ldval(const void* p, int idx, int dt32){
  return dt32 ? ((const float*)p)[idx] : bf2f(((const u16*)p)[idx]);
}
// wave-broadcast from per-lane register file (lane index literal via unroll)
__device__ __forceinline__ float rl(float v, int l){
  union { int i; float f; } c;
  c.i = __builtin_amdgcn_readlane(__float_as_int(v), l);
  return c.f;
}

// single-output 8-deep prefetch GEMV partial (bf16-pair weights)
template<int ITERS, int STRIDE>
__device__ __forceinline__ float gemv_bf(const u32* __restrict__ wp, const float* __restrict__ xp){
  float a0 = 0.f, a1 = 0.f;
  u32 wb[8];
  #pragma unroll
  for (int i = 0; i < 8; i++) wb[i] = wp[i * STRIDE];
  #pragma unroll 1
  for (int c = 0; c < ITERS - 8; c += 8){
    u32 wn[8];
    #pragma unroll
    for (int i = 0; i < 8; i++) wn[i] = wp[(c + 8 + i) * STRIDE];
    #pragma unroll
    for (int i = 0; i < 8; i++){
      float w0, w1; unp(wb[i], w0, w1);
      float2 x2 = *(const float2*)(xp + 2 * (c + i));
      a0 = fmaf(x2.x, w0, a0); a1 = fmaf(x2.y, w1, a1);
      wb[i] = wn[i];
    }
  }
  #pragma unroll
  for (int i = 0; i < 8; i++){
    float w0, w1; unp(wb[i], w0, w1);
    float2 x2 = *(const float2*)(xp + 2 * (ITERS - 8 + i));
    a0 = fmaf(x2.x, w0, a0); a1 = fmaf(x2.y, w1, a1);
  }
  return a0 + a1;
}

// dual-output GEMV partial: two weight streams share one x-read
template<int ITERS, int STRIDE>
__device__ __forceinline__ void gemv2_bf(const u32* __restrict__ wp0, const u32* __restrict__ wp1,
                                         const float* __restrict__ xp, float& r0, float& r1){
  float a0 = 0.f, a1 = 0.f, b0 = 0.f, b1 = 0.f;
  u32 wa[4], wb[4];
  #pragma unroll
  for (int i = 0; i < 4; i++){ wa[i] = wp0[i * STRIDE]; wb[i] = wp1[i * STRIDE]; }
  #pragma unroll 1
  for (int c = 0; c < ITERS - 4; c += 4){
    u32 na[4], nb[4];
    #pragma unroll
    for (int i = 0; i < 4; i++){ na[i] = wp0[(c + 4 + i) * STRIDE]; nb[i] = wp1[(c + 4 + i) * STRIDE]; }
    #pragma unroll
    for (int i = 0; i < 4; i++){
      float2 x2 = *(const float2*)(xp + 2 * (c + i));
      float w0, w1;
      unp(wa[i], w0, w1);
      a0 = fmaf(x2.x, w0, a0); a1 = fmaf(x2.y, w1, a1);
      unp(wb[i], w0, w1);
      b0 = fmaf(x2.x, w0, b0); b1 = fmaf(x2.y, w1, b1);
      wa[i] = na[i]; wb[i] = nb[i];
    }
  }
  #pragma unroll
  for (int i = 0; i < 4; i++){
    float2 x2 = *(const float2*)(xp + 2 * (ITERS - 4 + i));
    float w0, w1;
    unp(wa[i], w0, w1);
    a0 = fmaf(x2.x, w0, a0); a1 = fmaf(x2.y, w1, a1);
    unp(wb[i], w0, w1);
    b0 = fmaf(x2.x, w0, b0); b1 = fmaf(x2.y, w1, b1);
  }
  r0 = a0 + a1; r1 = b0 + b1;
}

// ---- dtype detect (flag=1 -> fp32 tensors, 0 -> bf16) ----
__global__ void detect_dtype(const u16* __restrict__ buf, int* __restrict__ flag){
  int lane = threadIdx.x;
  float crazy = 0.f;
  for (int i = 0; i < 4; i++){
    u16 v = buf[lane * 4 + i];
    int e = (v >> 7) & 0xFF;
    if (e != 0 && (e < 117 || e > 137)) crazy += 1.f;
  }
  crazy = wredsum(crazy);
  if (lane == 0) flag[0] = (crazy >= 32.f) ? 1 : 0;
}

__device__ __forceinline__ u16 rdbf(const void* s, size_t idx, int f32){
  return f32 ? f2bf(((const float*)s)[idx]) : ((const u16*)s)[idx];
}

__global__ void pack_w(const void* __restrict__ src, u32* __restrict__ dst,
                       int Js, int Jd, int K, const int* __restrict__ flag){
  int j = blockIdx.x * 256 + threadIdx.x;
  int k2 = blockIdx.y;
  if (j >= Jd) return;
  u16 lo = 0, hi = 0;
  if (j < Js){
    lo = rdbf(src, (size_t)j * K + 2 * k2, flag[0]);
    hi = rdbf(src, (size_t)j * K + 2 * k2 + 1, flag[0]);
  }
  dst[(size_t)k2 * Jd + j] = (u32)lo | ((u32)hi << 16);
}

__device__ __forceinline__ int permctl(int c){
  if (c < 128) return 5 * c;
  int q = c - 128; return 5 * (q & 127) + 1 + (q >> 7);
}
__device__ __forceinline__ int permout(int c){
  if (c < 128) return c;
  int q = c - 128; return 128 + 4 * (q & 127) + (q >> 7);
}

__global__ void pack_ctl(const void* __restrict__ src, u32* __restrict__ dst,
                         const int* __restrict__ flag){
  int j = blockIdx.x * 256 + threadIdx.x;
  int k2 = blockIdx.y;
  if (j >= 512) return;
  u16 lo = rdbf(src, (size_t)j * 640 + permctl(2 * k2), flag[0]);
  u16 hi = rdbf(src, (size_t)j * 640 + permctl(2 * k2 + 1), flag[0]);
  dst[(size_t)k2 * 512 + j] = (u32)lo | ((u32)hi << 16);
}

__global__ void pack_out(const void* __restrict__ src, u32* __restrict__ dst,
                         const int* __restrict__ flag){
  int j = threadIdx.x;
  int k2 = blockIdx.y;
  if (j >= 128) return;
  u16 lo = rdbf(src, (size_t)j * 640 + permout(2 * k2), flag[0]);
  u16 hi = rdbf(src, (size_t)j * 640 + permout(2 * k2 + 1), flag[0]);
  dst[(size_t)k2 * 128 + j] = (u32)lo | ((u32)hi << 16);
}

__global__ void fill_half(u16* __restrict__ p, int n){
  int i = blockIdx.x * 256 + threadIdx.x;
  if (i < n) p[i] = 0x3F00;
}

__global__ __launch_bounds__(NT) void dnc_main(
    const void* __restrict__ input,
    const void* __restrict__ enc_bih_g, const void* __restrict__ enc_bhh_g,
    const void* __restrict__ ctl_bih_g, const void* __restrict__ ctl_bhh_g,
    const void* __restrict__ iface_b_g, const void* __restrict__ out_b_g,
    const u32* __restrict__ encPW, const u32* __restrict__ ctlPW,
    const u32* __restrict__ ifPW, const u32* __restrict__ outPW,
    void* __restrict__ outp, const int* __restrict__ dtflag)
{
  const int bid = blockIdx.x;   // owner batch
  const int tid = threadIdx.x;
  const int lane = tid & 63;
  const int wid = tid >> 6;
  const int dt32 = dtflag[0];

  __shared__ __align__(16) float memS[Nv * 129];
  __shared__ __align__(16) float linkS[Nv * 129];
  __shared__ __align__(16) float pp[NT];
  __shared__ __align__(16) float ppE[NT];   // [0..256): out rv-part; [512..1024): out h-part
  __shared__ __align__(16) float xhC[768];  // [hE(128); rv r-major(512); hC(128)]
  __shared__ __align__(16) float xin2[2][128];
  __shared__ __align__(16) float rkeyS[512], rwS[512], rcS[512];  // rkeyS raw tanh; rcS raw dots / enc partials
  __shared__ __align__(16) float wkeyS[128], eraseS[128], wvecS[128];
  __shared__ __align__(16) float wwS[128], usageS[128], precS[128], wcS[128];
  __shared__ __align__(16) float uS[128], sortedU[128], scanA[128], alS[128], sqS[128];
  __shared__ __align__(16) float encBias[512], ctlBias[512];
  __shared__ __align__(16) float outBias[128];
  __shared__ float rstrS[4], fgS[4], rmRaw[12], rmS[12], scal[16];

  float cE = 0.f;   // enc cell: tids 896-1023 (w = tid-896)
  float cC = 0.f;   // ctl cell: tids 0-127

  // ---- init ----
  if (tid < 512){
    encBias[tid] = ldval(enc_bih_g, tid, dt32) + ldval(enc_bhh_g, tid, dt32);
    ctlBias[tid] = ldval(ctl_bih_g, tid, dt32) + ldval(ctl_bhh_g, tid, dt32);
    rwS[tid] = 0.f;
  }
  if (tid < 768) xhC[tid] = 0.f;
  if (tid < 128){
    outBias[tid] = ldval(out_b_g, tid, dt32);
    wwS[tid] = 0.f; usageS[tid] = 0.f; precS[tid] = 0.f;
  }
  for (int i = tid; i < Nv * 129; i += NT){ memS[i] = 0.f; linkS[i] = 0.f; }
  if (tid < 64){   // x(0) -> xin2[0]
    int idx = (bid * Tv + 0) * Wv + 2 * tid;
    xin2[0][2 * tid] = ldval(input, idx, dt32);
    xin2[0][2 * tid + 1] = ldval(input, idx + 1, dt32);
  } else if (tid >= 64 && tid < 128){   // x(1) -> xin2[1]
    int w2 = (tid - 64) * 2;
    int idx = (bid * Tv + 1) * Wv + w2;
    xin2[1][w2] = ldval(input, idx, dt32);
    xin2[1][w2 + 1] = ldval(input, idx + 1, dt32);
  }
  __syncthreads();

  // ---- preamble: encoder step 0 (Wih*x(0); Whh*0) ----
  if (tid >= 512 && tid < 768){
    int o = tid - 512;
    float r0, r1;
    gemv2_bf<64, 512>(encPW + o, encPW + o + 256, xin2[0], r0, r1);
    rcS[o] = r0; rcS[o + 256] = r1;
  }
  __syncthreads();
  if (tid >= 896){
    int w = tid - 896;
    float g0 = rcS[w] + encBias[w];
    float g1 = rcS[128 + w] + encBias[128 + w];
    float g2 = rcS[256 + w] + encBias[256 + w];
    float g3 = rcS[384 + w] + encBias[384 + w];
    float cn = sigm(g1) * cE + sigm(g0) * tanhf(g2);
    cE = cn;
    xhC[w] = sigm(g3) * tanhf(cn);   // hE(0)
  }
  __syncthreads();

  // =========================== main loop (11 barriers/step) ===========================
  for (int t = 0; t < Tv; ++t){
    // Ph1: ctl GEMV (w0-7) || enc Wih*x(t+1) (w8-11) || out-rv GEMV for t-1 (w12-15)
    if (tid < 512){
      int s = tid >> 8, o = tid & 255;
      float r0, r1;
      gemv2_bf<192, 512>(ctlPW + (s * 192) * 512 + o, ctlPW + (s * 192) * 512 + o + 256,
                         xhC + s * 384, r0, r1);
      pp[s * 512 + o] = r0;
      pp[s * 512 + o + 256] = r1;
    } else if (tid < 768){
      int o = tid - 512;
      float r0, r1;
      gemv2_bf<64, 512>(encPW + o, encPW + o + 256, xin2[(t + 1) & 1], r0, r1);
      rcS[o] = r0; rcS[o + 256] = r1;
    } else {
      int q = tid - 768;   // 256 threads
      int s = q >> 7, j = q & 127;
      ppE[q] = gemv_bf<128, 128>(outPW + (64 + s * 128) * 128 + j, xhC + 128 + 256 * s);
    }
    __syncthreads();

    // Ph2: ctl pointwise (0-127) || out(t-1) store (128-255) || enc Whh+combine -> rcS (512-767) || stage x(t+2) (768-831)
    if (tid < 128){
      float g0 = pp[tid] + pp[512 + tid] + ctlBias[tid];
      float g1 = pp[128 + tid] + pp[640 + tid] + ctlBias[128 + tid];
      float g2 = pp[256 + tid] + pp[768 + tid] + ctlBias[256 + tid];
      float g3 = pp[384 + tid] + pp[896 + tid] + ctlBias[384 + tid];
      float cn = sigm(g1) * cC + sigm(g0) * tanhf(g2);
      cC = cn;
      xhC[640 + tid] = sigm(g3) * tanhf(cn);   // hC(t)
    } else if (tid < 256){
      if (t > 0){
        int w = tid - 128;
        float o = outBias[w] + ppE[w] + ppE[128 + w]
                + ppE[512 + w] + ppE[640 + w] + ppE[768 + w] + ppE[896 + w];
        size_t oi = ((size_t)bid * Tv + (t - 1)) * Wv + w;
        if (dt32) ((float*)outp)[oi] = o;
        else ((u16*)outp)[oi] = f2bf(o);
      }
    } else if (tid >= 512 && tid < 768){
      int o = tid - 512;
      float r0, r1;
      gemv2_bf<64, 512>(encPW + 64 * 512 + o, encPW + 64 * 512 + o + 256, xhC, r0, r1);
      rcS[o] = rcS[o] + r0;
      rcS[o + 256] = rcS[o + 256] + r1;
    } else if (tid >= 768 && tid < 832){
      int w2 = (tid - 768) * 2;
      int col = (t + 2 < Tv) ? t + 2 : Tv - 1;
      int idx = (bid * Tv + col) * Wv + w2;
      xin2[t & 1][w2] = ldval(input, idx, dt32);
      xin2[t & 1][w2 + 1] = ldval(input, idx + 1, dt32);
    }
    __syncthreads();

    // Ph3: iface GEMV 2-out (0-463) || enc pointwise -> hE(t+1) (896-1023)
    if (tid < 464){
      float r0, r1;
      gemv2_bf<64, 928>(ifPW + tid, ifPW + tid + 464, xhC + 640, r0, r1);
      pp[tid] = r0 + ldval(iface_b_g, tid, dt32);
      pp[tid + 464] = r1 + ((tid + 464 < 919) ? ldval(iface_b_g, tid + 464, dt32) : 0.f);
    } else if (tid >= 896){
      int w = tid - 896;
      float g0 = rcS[w] + encBias[w];
      float g1 = rcS[128 + w] + encBias[128 + w];
      float g2 = rcS[256 + w] + encBias[256 + w];
      float g3 = rcS[384 + w] + encBias[384 + w];
      float cn = sigm(g1) * cE + sigm(g0) * tanhf(g2);
      cE = cn;
      xhC[w] = sigm(g3) * tanhf(cn);   // hE(t+1)
    }
    __syncthreads();

    // Ph4: parse xi (keys stay RAW; norms folded into scalars later)
    if (tid < 919){
      float v = pp[tid];
      if (tid < 512) rkeyS[tid] = tanhf(v);
      else if (tid < 516) rstrS[tid - 512] = softplusf(v);
      else if (tid < 644) wkeyS[tid - 516] = tanhf(v);
      else if (tid == 644) scal[0] = softplusf(v);
      else if (tid < 773) eraseS[tid - 645] = sigm(v);
      else if (tid < 901) wvecS[tid - 773] = tanhf(v);
      else if (tid < 905) fgS[tid - 901] = sigm(v);
      else if (tid == 905) scal[1] = sigm(v);
      else if (tid == 906) scal[2] = sigm(v);
      else rmRaw[tid - 907] = v;
    }
    __syncthreads();

    // Ph5': wc-dot partials (0-255) | rkey norms (256-511) | wkey norm (512-575)
    //       | usage+uS (576-703) | old-mem sq partials (704-959) | rm softmax (960-963)
    if (tid < 256){
      int n = tid & 127, hf = tid >> 7;    // hf uniform per wave
      float wk = wkeyS[hf * 64 + lane];
      const float* mrow = memS + n * 129 + hf * 64;
      float dt = 0.f;
      #pragma unroll 64
      for (int jj = 0; jj < 64; jj++) dt = fmaf(rl(wk, jj), mrow[jj], dt);
      pp[tid] = dt;
    } else if (tid < 512){
      int r = wid - 4;
      float a = rkeyS[r * 128 + lane], b = rkeyS[r * 128 + 64 + lane];
      float s = wredsum(a * a + b * b);
      if (lane == 0) scal[4 + r] = 1.f / (sqrtf(s) + DELTAv);
    } else if (tid < 576){
      float a = wkeyS[lane], b = wkeyS[64 + lane];
      float s = wredsum(a * a + b * b);
      if (lane == 0) scal[8] = 1.f / (sqrtf(s) + DELTAv);
    } else if (tid < 704){
      int n = tid - 576;
      float us = usageS[n];
      us = us + (1.f - us) * wwS[n];
      float ret = (1.f - fgS[0] * rwS[n]) * (1.f - fgS[1] * rwS[128 + n]) *
                  (1.f - fgS[2] * rwS[256 + n]) * (1.f - fgS[3] * rwS[384 + n]);
      us *= ret;
      usageS[n] = us;
      uS[n] = DELTAv + (1.f - DELTAv) * us;
    } else if (tid < 960){
      int q = tid - 704;
      int n = q & 127, hf = q >> 7;
      const float* mrow = memS + n * 129 + hf * 64;
      float sq = 0.f;
      #pragma unroll 64
      for (int jj = 0; jj < 64; jj++){ float m = mrow[jj]; sq = fmaf(m, m, sq); }
      pp[tid] = sq;   // pp[704+q]
    } else if (tid < 964){
      int r = tid - 960;
      float m0 = rmRaw[3 * r], m1 = rmRaw[3 * r + 1], m2 = rmRaw[3 * r + 2];
      float mx = fmaxf(m0, fmaxf(m1, m2));
      float e0 = __expf(m0 - mx), e1 = __expf(m1 - mx), e2 = __expf(m2 - mx);
      float s = e0 + e1 + e2;
      rmS[3 * r] = e0 / s; rmS[3 * r + 1] = e1 / s; rmS[3 * r + 2] = e2 / s;
    }
    __syncthreads();

    // Ph6': wc finalize+softmax (w0) || rank+scan+alloc (w1)
    if (wid == 0){
      float d0 = pp[lane] + pp[128 + lane];
      float d1 = pp[64 + lane] + pp[192 + lane];
      float q0 = pp[704 + lane] + pp[832 + lane];
      float q1 = pp[768 + lane] + pp[896 + lane];
      float kfac = scal[8] * scal[0];   // invKw * write_str
      float a  = d0 / (sqrtf(q0) + DELTAv) * kfac;
      float bq = d1 / (sqrtf(q1) + DELTAv) * kfac;
      float mx = wredmax(fmaxf(a, bq)); mx = __shfl(mx, 0, 64);
      float ea = __expf(a - mx), eb = __expf(bq - mx);
      float s = wredsum(ea + eb); s = __shfl(s, 0, 64);
      wcS[lane] = ea / s; wcS[lane + 64] = eb / s;
    } else if (wid == 1){
      int l = lane;
      float u0 = uS[l], u1 = uS[64 + l];
      int r0 = 0, r1 = 0;
      for (int m = 0; m < 128; m++){
        float um = uS[m];
        r0 += (um < u0) || (um == u0 && m < l);
        r1 += (um < u1) || (um == u1 && m < 64 + l);
      }
      sortedU[r0] = u0; sortedU[r1] = u1;
      float a = sortedU[2 * l], bq = sortedU[2 * l + 1];
      float p = a * bq;
      float incl = p;
      #pragma unroll
      for (int o = 1; o < 64; o <<= 1){
        float tv = __shfl_up(incl, o, 64);
        if (l >= o) incl *= tv;
      }
      float exh = __shfl_up(incl, 1, 64);
      if (l == 0) exh = 1.f;
      scanA[2 * l] = exh;
      scanA[2 * l + 1] = exh * a;
      float ex0 = scanA[r0], ex1 = scanA[r1];
      alS[l] = (1.f - u0) * ex0;
      alS[64 + l] = (1.f - u1) * ex1;
    }
    __syncthreads();

    // Ph7': write weighting + sum (w0)
    if (wid == 0){
      float w0v = scal[2] * (scal[1] * alS[lane] + (1.f - scal[1]) * wcS[lane]);
      float w1v = scal[2] * (scal[1] * alS[64 + lane] + (1.f - scal[1]) * wcS[64 + lane]);
      wwS[lane] = w0v; wwS[64 + lane] = w1v;
      float s = wredsum(w0v + w1v);
      if (lane == 0) scal[3] = s;
    }
    __syncthreads();

    // Ph8': mem erase/write + link update (16 waves)
    #pragma unroll
    for (int it = 0; it < 16; it++){
      int e = it * NT + tid;
      int n = e >> 7, w = e & 127;
      float wwn = wwS[n];
      float m = memS[n * 129 + w];
      memS[n * 129 + w] = m * (1.f - wwn * eraseS[w]) + wwn * wvecS[w];
      float l = linkS[n * 129 + w];
      linkS[n * 129 + w] = (n == w) ? 0.f
        : ((1.f - wwn - wwS[w]) * l + wwn * precS[w]);
    }
    __syncthreads();

    // Ph9': fw+bw 2-heads/thread (0-255) || rc dots 2-heads/thread + sq (256-511) || out-h GEMV (512-1023)
    if (tid < 256){
      int i = tid & 127, rg = tid >> 7;     // rg uniform per wave-pair
      int rA = 2 * rg, rB = rA + 1;
      float rwA0 = rwS[rA * 128 + lane], rwA1 = rwS[rA * 128 + 64 + lane];
      float rwB0 = rwS[rB * 128 + lane], rwB1 = rwS[rB * 128 + 64 + lane];
      float fA = 0.f, fB = 0.f, bA = 0.f, bB = 0.f;
      #pragma unroll 128
      for (int j = 0; j < 128; j++){
        float lr = linkS[i * 129 + j];
        float lc = linkS[j * 129 + i];
        float wA = rl((j < 64) ? rwA0 : rwA1, j & 63);
        float wB = rl((j < 64) ? rwB0 : rwB1, j & 63);
        fA = fmaf(wA, lr, fA); bA = fmaf(wA, lc, bA);
        fB = fmaf(wB, lr, fB); bB = fmaf(wB, lc, bB);
      }
      pp[rA * 128 + i] = fA; pp[rB * 128 + i] = fB;
      pp[512 + rA * 128 + i] = bA; pp[512 + rB * 128 + i] = bB;
    } else if (tid < 512){
      int q = tid - 256;
      int n = q & 127, rg = q >> 7;
      int rA = 2 * rg, rB = rA + 1;
      float kA0 = rkeyS[rA * 128 + lane], kA1 = rkeyS[rA * 128 + 64 + lane];
      float kB0 = rkeyS[rB * 128 + lane], kB1 = rkeyS[rB * 128 + 64 + lane];
      float sq = 0.f, dA = 0.f, dB = 0.f;
      #pragma unroll 128
      for (int j = 0; j < 128; j++){
        float m = memS[n * 129 + j];
        if (rg == 0) sq = fmaf(m, m, sq);
        dA = fmaf(rl((j < 64) ? kA0 : kA1, j & 63), m, dA);
        dB = fmaf(rl((j < 64) ? kB0 : kB1, j & 63), m, dB);
      }
      rcS[rA * 128 + n] = dA;
      rcS[rB * 128 + n] = dB;
      if (rg == 0) sqS[n] = sq;
    } else {
      int s = (tid - 512) >> 7, j = tid & 127;
      ppE[tid] = gemv_bf<16, 128>(outPW + (s * 16) * 128 + j, xhC + 640 + 32 * s);
    }
    __syncthreads();

    // Ph10': scaled rc softmax + new rw (w0-3) || prec update (256-383)
    if (wid < 4){
      int r = wid;
      float fac = scal[4 + r] * rstrS[r];    // invK_r * read_str_r
      float im0 = 1.f / (sqrtf(sqS[lane]) + DELTAv);
      float im1 = 1.f / (sqrtf(sqS[64 + lane]) + DELTAv);
      float a  = rcS[r * 128 + lane] * im0 * fac;
      float bq = rcS[r * 128 + 64 + lane] * im1 * fac;
      float mx = wredmax(fmaxf(a, bq)); mx = __shfl(mx, 0, 64);
      float ea = __expf(a - mx), eb = __expf(bq - mx);
      float s = wredsum(ea + eb); s = __shfl(s, 0, 64);
      float pa = ea / s, pb = eb / s;
      int o0 = r * 128 + lane, o1 = o0 + 64;
      rwS[o0] = rmS[3 * r] * pp[512 + o0] + rmS[3 * r + 1] * pp[o0] + rmS[3 * r + 2] * pa;
      rwS[o1] = rmS[3 * r] * pp[512 + o1] + rmS[3 * r + 1] * pp[o1] + rmS[3 * r + 2] * pb;
    } else if (tid >= 256 && tid < 384){
      int n = tid - 256;
      precS[n] = (1.f - scal[3]) * precS[n] + wwS[n];
    }
    __syncthreads();

    // Ph11': rv full-K readlane (w0-7) -> xhC rv slots
    if (tid < 512){
      int r = tid >> 7, w = tid & 127;
      float rw0 = rwS[r * 128 + lane], rw1 = rwS[r * 128 + 64 + lane];
      float acc = 0.f;
      #pragma unroll 128
      for (int n = 0; n < 128; n++)
        acc = fmaf(rl((n < 64) ? rw0 : rw1, n & 63), memS[n * 129 + w], acc);
      xhC[128 + tid] = acc;
    }
    __syncthreads();
  }

  // epilogue: out-rv for t = Tv-1, then final store
  if (tid < 256){
    int s = tid >> 7, j = tid & 127;
    ppE[tid] = gemv_bf<128, 128>(outPW + (64 + s * 128) * 128 + j, xhC + 128 + 256 * s);
  }
  __syncthreads();
  if (tid < 128){
    float o = outBias[tid] + ppE[tid] + ppE[128 + tid]
            + ppE[512 + tid] + ppE[640 + tid] + ppE[768 + tid] + ppE[896 + tid];
    size_t oi = ((size_t)bid * Tv + (Tv - 1)) * Wv + tid;
    if (dt32) ((float*)outp)[oi] = o;
    else ((u16*)outp)[oi] = f2bf(o);
  }
}

extern "C" void kernel_launch(void* const* d_in, const int* in_sizes, int n_in,
                              void* d_out, int out_size, void* d_ws, size_t ws_size,
                              hipStream_t stream) {
  (void)in_sizes; (void)n_in;
  const void* input   = d_in[0];
  const void* enc_Wih = d_in[2];
  const void* enc_Whh = d_in[3];
  const void* enc_bih = d_in[4];
  const void* enc_bhh = d_in[5];
  const void* ctl_Wih = d_in[6];
  const void* ctl_Whh = d_in[7];
  const void* ctl_bih = d_in[8];
  const void* ctl_bhh = d_in[9];
  const void* iface_W = d_in[10];
  const void* iface_b = d_in[11];
  const void* out_W   = d_in[12];
  const void* out_b   = d_in[13];

  char* ws = (char*)d_ws;
  size_t off = 0;
  int* dtflag = (int*)(ws + off); off += 256;
  u32* encPW = (u32*)(ws + off); off += (size_t)128 * 512 * 4;
  u32* ctlPW = (u32*)(ws + off); off += (size_t)384 * 512 * 4;
  u32* ifPW  = (u32*)(ws + off); off += (size_t)64 * 928 * 4;
  u32* outPW = (u32*)(ws + off); off += (size_t)320 * 128 * 4;
  const size_t need_bytes = off;   // ~1.45 MB (L2-resident)

  if (ws_size < need_bytes){
    fill_half<<<dim3((out_size + 255) / 256), dim3(256), 0, stream>>>((u16*)d_out, out_size);
    return;
  }

  detect_dtype<<<dim3(1), dim3(64), 0, stream>>>((const u16*)input, dtflag);

  pack_w<<<dim3(2, 64), 256, 0, stream>>>(enc_Wih, encPW, 512, 512, 128, dtflag);
  pack_w<<<dim3(2, 64), 256, 0, stream>>>(enc_Whh, encPW + 64 * 512, 512, 512, 128, dtflag);
  pack_ctl<<<dim3(2, 320), 256, 0, stream>>>(ctl_Wih, ctlPW, dtflag);
  pack_w<<<dim3(2, 64), 256, 0, stream>>>(ctl_Whh, ctlPW + 320 * 512, 512, 512, 128, dtflag);
  pack_w<<<dim3(4, 64), 256, 0, stream>>>(iface_W, ifPW, 919, 928, 128, dtflag);
  pack_out<<<dim3(1, 320), 128, 0, stream>>>(out_W, outPW, dtflag);

  dnc_main<<<dim3(Bv), dim3(NT), 0, stream>>>(
      input, enc_bih, enc_bhh, ctl_bih, ctl_bhh, iface_b, out_b,
      encPW, ctlPW, ifPW, outPW, d_out, dtflag);
}